// Round 7
// baseline (996.019 us; speedup 1.0000x reference)
//
#include <hip/hip_runtime.h>
#include <hip/hip_bf16.h>
#include <math.h>

#define B_ 4
#define T_ 2048
#define D_ 1024
#define F_ 2048
#define E_ 8
#define NT (B_ * T_)          // 8192 tokens
#define NS (NT * 2)           // 16384 routed assignments (K=2)
#define CAP (NS + E_ * 128)   // 17408 slots: 128-aligned per-expert segments always fit

typedef __attribute__((ext_vector_type(8))) short short8;
typedef __attribute__((ext_vector_type(4))) float floatx4;

static __device__ __forceinline__ unsigned short f2bf(float f) {
  union { float f; unsigned u; } a; a.f = f;
  unsigned r = a.u + 0x7fffu + ((a.u >> 16) & 1u);  // RNE
  return (unsigned short)(r >> 16);
}

static __device__ __forceinline__ float bf2f(unsigned u) {
  union { unsigned u; float f; } a; a.u = u << 16; return a.f;
}

static __device__ __forceinline__ void gld16(const unsigned short* g, unsigned short* l) {
  __builtin_amdgcn_global_load_lds(
      (const __attribute__((address_space(1))) void*)g,
      (__attribute__((address_space(3))) void*)l, 16, 0, 0);
}

// Branchless GELU: Abramowitz-Stegun 7.1.26 erf (|err| < 1.5e-7), hw exp2/rcp.
static __device__ __forceinline__ float gelu_f(float v) {
  float ax = fabsf(v) * 0.70710678118654752f;
  float t = __builtin_amdgcn_rcpf(1.f + 0.3275911f * ax);
  float e = __builtin_amdgcn_exp2f(-ax * ax * 1.44269504088896f);  // exp(-ax^2)
  float p = t * (0.254829592f +
            t * (-0.284496736f +
            t * (1.421413741f +
            t * (-1.453152027f +
            t * 1.061405429f))));
  float er = 1.f - p * e;
  er = copysignf(er, v);
  return 0.5f * v * (1.f + er);
}

// ---- both weight transposes in ONE launch: id<512 -> w1 tile, else w2 tile.
// 64x64 tile, 256 threads: float4 coalesced reads, uint4 (8 bf16) coalesced
// writes, LDS 2-way both sides (free).
__global__ void transpose_cvt(const float* __restrict__ w1, const float* __restrict__ w2,
                              unsigned short* __restrict__ w1t, unsigned short* __restrict__ w2t) {
  __shared__ float tile[64][65];
  int id = blockIdx.x;              // 0..1023
  bool second = id >= 512;
  int lid = second ? id - 512 : id;
  int R = second ? F_ : D_, C = second ? D_ : F_;
  int nx = C / 64;
  int ty = lid / nx, tx = lid - ty * nx;
  const float* inp = (second ? w2 : w1) + (size_t)blockIdx.y * R * C;
  unsigned short* outp = (second ? w2t : w1t) + (size_t)blockIdx.y * R * C;
  int c0 = tx * 64, r0 = ty * 64;
  int tid = threadIdx.x;            // 256
  int rl = tid >> 4;                // 0..15
  int cl = (tid & 15) * 4;          // 0,4,..,60
#pragma unroll
  for (int jr = 0; jr < 4; jr++) {
    int row = rl + 16 * jr;
    float4 v = *(const float4*)&inp[(size_t)(r0 + row) * C + c0 + cl];
    tile[row][cl + 0] = v.x; tile[row][cl + 1] = v.y;
    tile[row][cl + 2] = v.z; tile[row][cl + 3] = v.w;
  }
  __syncthreads();
  int cc0 = tid >> 3;               // 0..31
  int rq = (tid & 7) * 8;           // 0,8,..,56
#pragma unroll
  for (int jc = 0; jc < 2; jc++) {
    int cc = cc0 + 32 * jc;
    unsigned w[4];
#pragma unroll
    for (int i = 0; i < 4; i++) {
      unsigned lo = f2bf(tile[rq + 2 * i][cc]);
      unsigned hi = f2bf(tile[rq + 2 * i + 1][cc]);
      w[i] = lo | (hi << 16);
    }
    *(uint4*)&outp[(size_t)(c0 + cc) * R + r0 + rq] = make_uint4(w[0], w[1], w[2], w[3]);
  }
}

// ---- router: fp32 logits, top-2, softmax over the pair. NO atomics.
// Fused: zero-fill of out (exact float4 cover) and wt_of (pad-slot weights) —
// makes the atomic-combine epilogue idempotent per launch. ----
__global__ void router_k(const float* __restrict__ x, const float* __restrict__ gw,
                         const float* __restrict__ gb, int* __restrict__ ti,
                         float* __restrict__ tw, float* __restrict__ out,
                         float* __restrict__ wt_of) {
  int gtid = blockIdx.x * 256 + threadIdx.x;   // 0..524287
  float4 z = {0.f, 0.f, 0.f, 0.f};
  float4* ob = (float4*)out;                   // NT*D_/4 = 2097152 float4
#pragma unroll
  for (int j = 0; j < 4; j++) ob[gtid + j * (NT * D_ / 16)] = z;
  if (gtid < CAP) wt_of[gtid] = 0.f;

  int wid = threadIdx.x >> 6, lane = threadIdx.x & 63;
  int t = blockIdx.x * 4 + wid;
  const float* xr = x + (size_t)t * D_;
  float acc[E_];
#pragma unroll
  for (int e = 0; e < E_; e++) acc[e] = 0.f;
#pragma unroll
  for (int it = 0; it < D_ / 64; it++) {
    int d = it * 64 + lane;
    float xv = xr[d];
    const float* g = gw + d * E_;
#pragma unroll
    for (int e = 0; e < E_; e++) acc[e] += xv * g[e];
  }
#pragma unroll
  for (int off = 32; off > 0; off >>= 1)
#pragma unroll
    for (int e = 0; e < E_; e++) acc[e] += __shfl_xor(acc[e], off);
  if (lane == 0) {
    float v[E_];
#pragma unroll
    for (int e = 0; e < E_; e++) v[e] = acc[e] + gb[e];
    int i0 = 0; float v0 = v[0];
#pragma unroll
    for (int e = 1; e < E_; e++) if (v[e] > v0) { v0 = v[e]; i0 = e; }
    int i1 = -1; float v1 = -3.4e38f;
#pragma unroll
    for (int e = 0; e < E_; e++) if (e != i0 && v[e] > v1) { v1 = v[e]; i1 = e; }
    float ex = expf(v1 - v0);           // <= 1, no overflow
    float w0 = 1.f / (1.f + ex);
    float w1 = ex / (1.f + ex);
    ti[2 * t] = i0; tw[2 * t] = w0;
    ti[2 * t + 1] = i1; tw[2 * t + 1] = w1;
  }
}

// ---- single-block histogram + 128-aligned exclusive prefix ----
__global__ void count_prefix_k(const int* __restrict__ ti, int* __restrict__ offs,
                               int* __restrict__ cursors) {
  __shared__ int scnt[4][E_];
  int tid = threadIdx.x;  // 256 threads
  int cnt[E_];
#pragma unroll
  for (int k = 0; k < E_; k++) cnt[k] = 0;
  for (int i = tid; i < NS; i += 256) {
    int e = ti[i];
#pragma unroll
    for (int k = 0; k < E_; k++) cnt[k] += (e == k) ? 1 : 0;
  }
#pragma unroll
  for (int off = 32; off > 0; off >>= 1)
#pragma unroll
    for (int k = 0; k < E_; k++) cnt[k] += __shfl_xor(cnt[k], off);
  int wid = tid >> 6, lane = tid & 63;
  if (lane == 0)
#pragma unroll
    for (int k = 0; k < E_; k++) scnt[wid][k] = cnt[k];
  __syncthreads();
  if (tid == 0) {
    int o = 0;
    for (int k = 0; k < E_; k++) {
      int c = scnt[0][k] + scnt[1][k] + scnt[2][k] + scnt[3][k];
      offs[k] = o;
      cursors[k] = o;
      o += (c + 127) & ~127;
    }
    offs[E_] = o;
  }
}

// ---- wave-aggregated scatter: 8 atomics per wave. Writes per-slot token (idx)
// and per-slot combine weight (wt_of; pads stay router-zeroed). ----
__global__ void scatter_k(const int* __restrict__ ti, const float* __restrict__ tw,
                          int* __restrict__ cursors, int* __restrict__ idx,
                          float* __restrict__ wt_of) {
  int a = blockIdx.x * 256 + threadIdx.x;  // 0..NS-1
  int lane = threadIdx.x & 63;
  int e = ti[a];
  unsigned long long m[E_];
#pragma unroll
  for (int k = 0; k < E_; k++) m[k] = __ballot(e == k);
  int base = 0;
  if (lane < E_) base = atomicAdd(&cursors[lane], __popcll(m[lane]));
  int myBase = __shfl(base, e);
  unsigned long long m_mine = 0;
#pragma unroll
  for (int k = 0; k < E_; k++) if (e == k) m_mine = m[k];
  int rank = __popcll(m_mine & ((1ull << lane) - 1ull));
  int pos = myBase + rank;
  idx[pos] = a >> 1;
  wt_of[pos] = tw[a];
}

// ---- gather routed token rows into bf16, slot-major. Pad slots hold stale
// garbage in idx: clamp into [0,NT) — their combine weight is 0. ----
__global__ void gather_k(const float* __restrict__ x, const int* __restrict__ idx,
                         unsigned short* __restrict__ Xg) {
  int s = blockIdx.x;
  int t = idx[s];
  t = ((unsigned)t < (unsigned)NT) ? t : 0;
  const float4* xr = (const float4*)(x + (size_t)t * D_);
  float4 v = xr[threadIdx.x];
  uint2 p;
  p.x = (unsigned)f2bf(v.x) | ((unsigned)f2bf(v.y) << 16);
  p.y = (unsigned)f2bf(v.z) | ((unsigned)f2bf(v.w) << 16);
  ((uint2*)(Xg + (size_t)s * D_))[threadIdx.x] = p;
}

// ---- grouped GEMM: 128x128 tile, BK=32, 4 waves (2Mx2N), DOUBLE-buffered LDS
// (32 KB -> 5 blocks/CU = 20 waves/CU), stage-early + one vmcnt(0)+barrier per
// K-step (T3-minimum). R5 showed 25% MfmaUtil at 3 blocks/CU with all pipes
// idle (latency-bound, phase-aligned blocks); this trades schedule depth for
// TLP — 5-way block overlap covers the per-phase serial latency (m114).
// Next-step loads are issued at the TOP of each step (~250+ cyc before the
// drain; L2-hit ~200 cyc) so vmcnt(0) is cheap.
//
// + XCD-aware swizzle (T1, R5-verified: FETCH 300->83 MB): h -> logical =
// (h&7)*(nwg/8) + h>>3 (bijective, nwg%8==0); each XCD owns contiguous
// row-tiles so A-strips and W panels are L2/L3-resident.
//
// LDS swizzle (BK=32, 64-B rows, PMC-verified 0 conflicts): phys 16-B chunk of
// logical (row r, k-chunk q) = (((r&1)<<2)|q) ^ ((r>>1)&7) within each 128-B
// superrow-pair. Staging keeps LDS dest linear (gld16 requirement) and
// pre-permutes the per-lane GLOBAL source: lane i covers logical (r_l,q_l)
// with c = (i&7)^(i>>3), r_l = (i>>3)*2 + (c>>2), q_l = c&3.
//
// ATOMIC epilogue (gemm2): out[tok] += w*(acc+bias) in f32 via global atomics —
// fuses the combine pass (deletes combine_k + Yg round-trip; more accurate:
// weights applied before bf16 rounding). Pad slots: w=0, token clamped.
template <int K, int N, bool GELU, bool ATOMIC>
__global__ __launch_bounds__(256, 5) void gemm_k(const unsigned short* __restrict__ A,
                                                 const unsigned short* __restrict__ W,
                                                 const float* __restrict__ bias_all,
                                                 unsigned short* __restrict__ O,
                                                 const int* __restrict__ offs,
                                                 const int* __restrict__ idxp,
                                                 const float* __restrict__ wtp,
                                                 float* __restrict__ outp) {
  constexpr int NC = N / 128;
  int h = blockIdx.x;
  int logical = (h & 7) * ((int)gridDim.x >> 3) + (h >> 3);
  int rt = logical / NC, ct = logical - rt * NC;   // NC is a power of 2
  int slot0 = rt * 128;
  if (slot0 >= offs[E_]) return;
  int e = 0;
  while (slot0 >= offs[e + 1]) e++;
  const unsigned short* Bp = W + (size_t)e * N * K;
  int n0 = ct * 128;

  __shared__ unsigned short lA[2][128 * 32];
  __shared__ unsigned short lB[2][128 * 32];

  int tid = threadIdx.x;
  int wid = tid >> 6, lane = tid & 63;
  int wr = wid >> 1, wc = wid & 1;          // 2M x 2N wave grid, per-wave out 64x64
  int quad = lane >> 4, l15 = lane & 15;

  // LDS read bases (shorts): row r = 16-aligned base + l15 -> (r>>1)&7 = (l15>>1)&7
  int cph = (((l15 & 1) << 2) | quad) ^ ((l15 >> 1) & 7);
  int ra = ((wr << 5) + (l15 >> 1)) * 64 + cph * 8;   // + m*512 per 16-row frag
  int rb = ((wc << 5) + (l15 >> 1)) * 64 + cph * 8;   // + n*512

  // staging lane map (see header comment); wave stages rows 32wid..32wid+31
  int srl = lane >> 3;
  int clog = (lane & 7) ^ srl;
  int r_l = (srl << 1) | (clog >> 2);
  int q_l = clog & 3;
  const unsigned short* gA = A + (size_t)(slot0 + 32 * wid + r_l) * K + q_l * 8;
  const unsigned short* gB = Bp + (size_t)(n0 + 32 * wid + r_l) * K + q_l * 8;

#define STG(buf, kt) do {                                                \
    gld16(gA + (size_t)(kt) * 32, &lA[buf][(32 * wid) * 32]);            \
    gld16(gA + (size_t)16 * K + (size_t)(kt) * 32,                       \
          &lA[buf][(32 * wid + 16) * 32]);                               \
    gld16(gB + (size_t)(kt) * 32, &lB[buf][(32 * wid) * 32]);            \
    gld16(gB + (size_t)16 * K + (size_t)(kt) * 32,                       \
          &lB[buf][(32 * wid + 16) * 32]);                               \
  } while (0)
#define SYNC0 asm volatile("s_waitcnt vmcnt(0)\n\ts_barrier" ::: "memory")

  floatx4 acc[4][4];
#pragma unroll
  for (int mi = 0; mi < 4; mi++)
#pragma unroll
    for (int ni = 0; ni < 4; ni++) acc[mi][ni] = (floatx4){0.f, 0.f, 0.f, 0.f};

  constexpr int NK = K / 32;

  // prologue: stage K-step 0, drain
  STG(0, 0);
  SYNC0;

#define STEP(bufc, t) do {                                               \
    int kt = ((t) + 1 < NK) ? (t) + 1 : 0;  /* dummy keeps waits uniform */ \
    STG((bufc) ^ 1, kt);                                                 \
    short8 af[4], bfr[4];                                                \
    _Pragma("unroll")                                                    \
    for (int m = 0; m < 4; m++) af[m] = *(const short8*)&lA[bufc][ra + m * 512]; \
    _Pragma("unroll")                                                    \
    for (int n = 0; n < 4; n++) bfr[n] = *(const short8*)&lB[bufc][rb + n * 512]; \
    _Pragma("unroll")                                                    \
    for (int m = 0; m < 4; m++)                                          \
      _Pragma("unroll")                                                  \
      for (int n = 0; n < 4; n++)                                        \
        acc[m][n] = __builtin_amdgcn_mfma_f32_16x16x32_bf16(af[m], bfr[n], acc[m][n], 0, 0, 0); \
    SYNC0;                                                               \
  } while (0)

  for (int t2 = 0; t2 < NK; t2 += 2) {  // NK even
    STEP(0, t2);
    STEP(1, t2 + 1);
  }
#undef STEP
#undef STG
#undef SYNC0

  const float* bias = bias_all + (size_t)e * N;
  if constexpr (ATOMIC) {
#pragma unroll
    for (int mi = 0; mi < 4; mi++) {
      int srow = slot0 + 64 * wr + 16 * mi + quad * 4;
#pragma unroll
      for (int r = 0; r < 4; r++) {
        int slot = srow + r;
        int tok = idxp[slot];
        tok = ((unsigned)tok < (unsigned)NT) ? tok : 0;
        float w = wtp[slot];
        float* orow = outp + (size_t)tok * D_;
#pragma unroll
        for (int ni = 0; ni < 4; ni++) {
          int col = n0 + 64 * wc + 16 * ni + l15;
          atomicAdd(&orow[col], w * (acc[mi][ni][r] + bias[col]));
        }
      }
    }
  } else {
#pragma unroll
    for (int mi = 0; mi < 4; mi++) {
      int row = slot0 + 64 * wr + 16 * mi + quad * 4;
#pragma unroll
      for (int ni = 0; ni < 4; ni++) {
        int col = n0 + 64 * wc + 16 * ni + l15;
        float bv = bias[col];
#pragma unroll
        for (int r = 0; r < 4; r++) {
          float v = acc[mi][ni][r] + bv;
          if (GELU) v = gelu_f(v);
          O[(size_t)(row + r) * N + col] = f2bf(v);
        }
      }
    }
  }
}

extern "C" void kernel_launch(void* const* d_in, const int* in_sizes, int n_in,
                              void* d_out, int out_size, void* d_ws, size_t ws_size,
                              hipStream_t stream) {
  const float* x  = (const float*)d_in[0];
  const float* gw = (const float*)d_in[1];
  const float* gb = (const float*)d_in[2];
  const float* w1 = (const float*)d_in[3];
  const float* b1 = (const float*)d_in[4];
  const float* w2 = (const float*)d_in[5];
  const float* b2 = (const float*)d_in[6];
  float* out = (float*)d_out;

  char* p = (char*)d_ws;
  unsigned short* w1t = (unsigned short*)p; p += (size_t)E_ * D_ * F_ * 2;
  unsigned short* w2t = (unsigned short*)p; p += (size_t)E_ * D_ * F_ * 2;
  unsigned short* Xg  = (unsigned short*)p; p += (size_t)CAP * D_ * 2;
  unsigned short* H   = (unsigned short*)p; p += (size_t)CAP * F_ * 2;
  int*   idx    = (int*)p; p += (size_t)CAP * 4;
  float* wt_of  = (float*)p; p += (size_t)CAP * 4;
  int*   ti     = (int*)p; p += (size_t)NS * 4;
  float* tw     = (float*)p; p += (size_t)NS * 4;
  int* cursors = (int*)p; p += 64;
  int* offs    = (int*)p; p += 64;

  transpose_cvt<<<dim3(1024, E_), 256, 0, stream>>>(w1, w2, w1t, w2t);
  router_k<<<NT / 4, 256, 0, stream>>>(x, gw, gb, ti, tw, out, wt_of);
  count_prefix_k<<<1, 256, 0, stream>>>(ti, offs, cursors);
  scatter_k<<<NS / 256, 256, 0, stream>>>(ti, tw, cursors, idx, wt_of);
  gather_k<<<CAP, 256, 0, stream>>>(x, idx, Xg);
  gemm_k<D_, F_, true, false><<<dim3((CAP / 128) * (F_ / 128)), 256, 0, stream>>>(
      Xg, w1t, b1, H, offs, nullptr, nullptr, nullptr);
  gemm_k<F_, D_, false, true><<<dim3((CAP / 128) * (D_ / 128)), 256, 0, stream>>>(
      H, w2t, b2, nullptr, offs, idx, wt_of, out);
}

// Round 8
// 536.840 us; speedup vs baseline: 1.8553x; 1.8553x over previous
//
#include <hip/hip_runtime.h>
#include <hip/hip_bf16.h>
#include <math.h>

#define B_ 4
#define T_ 2048
#define D_ 1024
#define F_ 2048
#define E_ 8
#define NT (B_ * T_)          // 8192 tokens
#define NS (NT * 2)           // 16384 routed assignments (K=2)
#define CAP (NS + E_ * 128)   // 17408 slots: 128-aligned per-expert segments always fit

typedef __attribute__((ext_vector_type(8))) short short8;
typedef __attribute__((ext_vector_type(4))) float floatx4;

static __device__ __forceinline__ unsigned short f2bf(float f) {
  union { float f; unsigned u; } a; a.f = f;
  unsigned r = a.u + 0x7fffu + ((a.u >> 16) & 1u);  // RNE
  return (unsigned short)(r >> 16);
}

static __device__ __forceinline__ float bf2f(unsigned u) {
  union { unsigned u; float f; } a; a.u = u << 16; return a.f;
}

static __device__ __forceinline__ void gld16(const unsigned short* g, unsigned short* l) {
  __builtin_amdgcn_global_load_lds(
      (const __attribute__((address_space(1))) void*)g,
      (__attribute__((address_space(3))) void*)l, 16, 0, 0);
}

// Branchless GELU: Abramowitz-Stegun 7.1.26 erf (|err| < 1.5e-7), hw exp2/rcp.
static __device__ __forceinline__ float gelu_f(float v) {
  float ax = fabsf(v) * 0.70710678118654752f;
  float t = __builtin_amdgcn_rcpf(1.f + 0.3275911f * ax);
  float e = __builtin_amdgcn_exp2f(-ax * ax * 1.44269504088896f);  // exp(-ax^2)
  float p = t * (0.254829592f +
            t * (-0.284496736f +
            t * (1.421413741f +
            t * (-1.453152027f +
            t * 1.061405429f))));
  float er = 1.f - p * e;
  er = copysignf(er, v);
  return 0.5f * v * (1.f + er);
}

// ---- both weight transposes in ONE launch: id<512 -> w1 tile, else w2 tile.
// 64x64 tile, 256 threads: float4 coalesced reads, uint4 (8 bf16) coalesced
// writes, LDS 2-way both sides (free).
__global__ void transpose_cvt(const float* __restrict__ w1, const float* __restrict__ w2,
                              unsigned short* __restrict__ w1t, unsigned short* __restrict__ w2t) {
  __shared__ float tile[64][65];
  int id = blockIdx.x;              // 0..1023
  bool second = id >= 512;
  int lid = second ? id - 512 : id;
  int R = second ? F_ : D_, C = second ? D_ : F_;
  int nx = C / 64;
  int ty = lid / nx, tx = lid - ty * nx;
  const float* inp = (second ? w2 : w1) + (size_t)blockIdx.y * R * C;
  unsigned short* outp = (second ? w2t : w1t) + (size_t)blockIdx.y * R * C;
  int c0 = tx * 64, r0 = ty * 64;
  int tid = threadIdx.x;            // 256
  int rl = tid >> 4;                // 0..15
  int cl = (tid & 15) * 4;          // 0,4,..,60
#pragma unroll
  for (int jr = 0; jr < 4; jr++) {
    int row = rl + 16 * jr;
    float4 v = *(const float4*)&inp[(size_t)(r0 + row) * C + c0 + cl];
    tile[row][cl + 0] = v.x; tile[row][cl + 1] = v.y;
    tile[row][cl + 2] = v.z; tile[row][cl + 3] = v.w;
  }
  __syncthreads();
  int cc0 = tid >> 3;               // 0..31
  int rq = (tid & 7) * 8;           // 0,8,..,56
#pragma unroll
  for (int jc = 0; jc < 2; jc++) {
    int cc = cc0 + 32 * jc;
    unsigned w[4];
#pragma unroll
    for (int i = 0; i < 4; i++) {
      unsigned lo = f2bf(tile[rq + 2 * i][cc]);
      unsigned hi = f2bf(tile[rq + 2 * i + 1][cc]);
      w[i] = lo | (hi << 16);
    }
    *(uint4*)&outp[(size_t)(c0 + cc) * R + r0 + rq] = make_uint4(w[0], w[1], w[2], w[3]);
  }
}

// ---- router: fp32 logits, top-2, softmax over the pair. NO atomics.
// Fused: zero-fill of out (exact float4 cover) and wt_of (pad-slot weights) —
// makes the atomic-combine epilogue idempotent per launch. ----
__global__ void router_k(const float* __restrict__ x, const float* __restrict__ gw,
                         const float* __restrict__ gb, int* __restrict__ ti,
                         float* __restrict__ tw, float* __restrict__ out,
                         float* __restrict__ wt_of) {
  int gtid = blockIdx.x * 256 + threadIdx.x;   // 0..524287
  float4 z = {0.f, 0.f, 0.f, 0.f};
  float4* ob = (float4*)out;                   // NT*D_/4 = 2097152 float4
#pragma unroll
  for (int j = 0; j < 4; j++) ob[gtid + j * (NT * D_ / 16)] = z;
  if (gtid < CAP) wt_of[gtid] = 0.f;

  int wid = threadIdx.x >> 6, lane = threadIdx.x & 63;
  int t = blockIdx.x * 4 + wid;
  const float* xr = x + (size_t)t * D_;
  float acc[E_];
#pragma unroll
  for (int e = 0; e < E_; e++) acc[e] = 0.f;
#pragma unroll
  for (int it = 0; it < D_ / 64; it++) {
    int d = it * 64 + lane;
    float xv = xr[d];
    const float* g = gw + d * E_;
#pragma unroll
    for (int e = 0; e < E_; e++) acc[e] += xv * g[e];
  }
#pragma unroll
  for (int off = 32; off > 0; off >>= 1)
#pragma unroll
    for (int e = 0; e < E_; e++) acc[e] += __shfl_xor(acc[e], off);
  if (lane == 0) {
    float v[E_];
#pragma unroll
    for (int e = 0; e < E_; e++) v[e] = acc[e] + gb[e];
    int i0 = 0; float v0 = v[0];
#pragma unroll
    for (int e = 1; e < E_; e++) if (v[e] > v0) { v0 = v[e]; i0 = e; }
    int i1 = -1; float v1 = -3.4e38f;
#pragma unroll
    for (int e = 0; e < E_; e++) if (e != i0 && v[e] > v1) { v1 = v[e]; i1 = e; }
    float ex = expf(v1 - v0);           // <= 1, no overflow
    float w0 = 1.f / (1.f + ex);
    float w1 = ex / (1.f + ex);
    ti[2 * t] = i0; tw[2 * t] = w0;
    ti[2 * t + 1] = i1; tw[2 * t + 1] = w1;
  }
}

// ---- single-block histogram + 128-aligned exclusive prefix ----
__global__ void count_prefix_k(const int* __restrict__ ti, int* __restrict__ offs,
                               int* __restrict__ cursors) {
  __shared__ int scnt[4][E_];
  int tid = threadIdx.x;  // 256 threads
  int cnt[E_];
#pragma unroll
  for (int k = 0; k < E_; k++) cnt[k] = 0;
  for (int i = tid; i < NS; i += 256) {
    int e = ti[i];
#pragma unroll
    for (int k = 0; k < E_; k++) cnt[k] += (e == k) ? 1 : 0;
  }
#pragma unroll
  for (int off = 32; off > 0; off >>= 1)
#pragma unroll
    for (int k = 0; k < E_; k++) cnt[k] += __shfl_xor(cnt[k], off);
  int wid = tid >> 6, lane = tid & 63;
  if (lane == 0)
#pragma unroll
    for (int k = 0; k < E_; k++) scnt[wid][k] = cnt[k];
  __syncthreads();
  if (tid == 0) {
    int o = 0;
    for (int k = 0; k < E_; k++) {
      int c = scnt[0][k] + scnt[1][k] + scnt[2][k] + scnt[3][k];
      offs[k] = o;
      cursors[k] = o;
      o += (c + 127) & ~127;
    }
    offs[E_] = o;
  }
}

// ---- wave-aggregated scatter: 8 atomics per wave. Writes per-slot token (idx)
// and per-slot combine weight (wt_of; pads stay router-zeroed). ----
__global__ void scatter_k(const int* __restrict__ ti, const float* __restrict__ tw,
                          int* __restrict__ cursors, int* __restrict__ idx,
                          float* __restrict__ wt_of) {
  int a = blockIdx.x * 256 + threadIdx.x;  // 0..NS-1
  int lane = threadIdx.x & 63;
  int e = ti[a];
  unsigned long long m[E_];
#pragma unroll
  for (int k = 0; k < E_; k++) m[k] = __ballot(e == k);
  int base = 0;
  if (lane < E_) base = atomicAdd(&cursors[lane], __popcll(m[lane]));
  int myBase = __shfl(base, e);
  unsigned long long m_mine = 0;
#pragma unroll
  for (int k = 0; k < E_; k++) if (e == k) m_mine = m[k];
  int rank = __popcll(m_mine & ((1ull << lane) - 1ull));
  int pos = myBase + rank;
  idx[pos] = a >> 1;
  wt_of[pos] = tw[a];
}

// ---- gather routed token rows into bf16, slot-major. Pad slots hold stale
// garbage in idx: clamp into [0,NT) — their combine weight is 0. ----
__global__ void gather_k(const float* __restrict__ x, const int* __restrict__ idx,
                         unsigned short* __restrict__ Xg) {
  int s = blockIdx.x;
  int t = idx[s];
  t = ((unsigned)t < (unsigned)NT) ? t : 0;
  const float4* xr = (const float4*)(x + (size_t)t * D_);
  float4 v = xr[threadIdx.x];
  uint2 p;
  p.x = (unsigned)f2bf(v.x) | ((unsigned)f2bf(v.y) << 16);
  p.y = (unsigned)f2bf(v.z) | ((unsigned)f2bf(v.w) << 16);
  ((uint2*)(Xg + (size_t)s * D_))[threadIdx.x] = p;
}

// ---- grouped GEMM: 128x128 tile, BK=32, 4 waves (2Mx2N), 3-buffer LDS
// rotation, counted vmcnt (never 0), one barrier per K-step — byte-identical
// schedule to the R5-measured kernel (118.5 µs, MfmaUtil 25%, FETCH 83 MB).
// __launch_bounds__(256,3): acc = 64 AGPR + ~68 arch VGPR = ~132 regs/lane
// unified; 3 waves/EU needs <=170 (fits). R7 measured the (256,5) version:
// budget ~102 -> accumulator spilled to scratch (VGPR 48, gemm1 WRITE 726 MB,
// MfmaUtil 1-7%, 3.5x slower). 4 waves/EU is the ceiling; 3 is safe.
//
// + XCD-aware swizzle (T1, R5-verified: FETCH 300->83 MB): h -> logical =
// (h&7)*(nwg/8) + h>>3 (bijective, nwg%8==0); each XCD owns contiguous
// row-tiles so A-strips and W panels are L2/L3-resident.
//
// LDS swizzle (BK=32, 64-B rows, PMC-verified 0 conflicts): phys 16-B chunk of
// logical (row r, k-chunk q) = (((r&1)<<2)|q) ^ ((r>>1)&7) within each 128-B
// superrow-pair. Staging keeps LDS dest linear (gld16 requirement) and
// pre-permutes the per-lane GLOBAL source: lane i covers logical (r_l,q_l)
// with c = (i&7)^(i>>3), r_l = (i>>3)*2 + (c>>2), q_l = c&3.
//
// Ledger per wave: entering step t, outstanding = step t+1's 4 gld16; step t
// issues 4 for t+2 -> 8; vmcnt(4) before the barrier retires exactly t+1's
// group. Tail dummy-stages kt=0. Buffer indices compile-time (unroll by 3).
//
// ATOMIC epilogue (gemm2): out[tok] += w*(acc+bias) in f32 via global atomics —
// fuses the combine pass (deletes combine_k + Yg bf16 round-trip; more
// accurate: weights applied before rounding). Pad slots: w=0, token clamped.
template <int K, int N, bool GELU, bool ATOMIC>
__global__ __launch_bounds__(256, 3) void gemm_k(const unsigned short* __restrict__ A,
                                                 const unsigned short* __restrict__ W,
                                                 const float* __restrict__ bias_all,
                                                 unsigned short* __restrict__ O,
                                                 const int* __restrict__ offs,
                                                 const int* __restrict__ idxp,
                                                 const float* __restrict__ wtp,
                                                 float* __restrict__ outp) {
  constexpr int NC = N / 128;
  int h = blockIdx.x;
  int logical = (h & 7) * ((int)gridDim.x >> 3) + (h >> 3);
  int rt = logical / NC, ct = logical - rt * NC;   // NC is a power of 2
  int slot0 = rt * 128;
  if (slot0 >= offs[E_]) return;
  int e = 0;
  while (slot0 >= offs[e + 1]) e++;
  const unsigned short* Bp = W + (size_t)e * N * K;
  int n0 = ct * 128;

  __shared__ unsigned short lA[3][128 * 32];
  __shared__ unsigned short lB[3][128 * 32];

  int tid = threadIdx.x;
  int wid = tid >> 6, lane = tid & 63;
  int wr = wid >> 1, wc = wid & 1;          // 2M x 2N wave grid, per-wave out 64x64
  int quad = lane >> 4, l15 = lane & 15;

  // LDS read bases (shorts): row r = 16-aligned base + l15 -> (r>>1)&7 = (l15>>1)&7
  int cph = (((l15 & 1) << 2) | quad) ^ ((l15 >> 1) & 7);
  int ra = ((wr << 5) + (l15 >> 1)) * 64 + cph * 8;   // + m*512 per 16-row frag
  int rb = ((wc << 5) + (l15 >> 1)) * 64 + cph * 8;   // + n*512

  // staging lane map (see header comment); wave stages rows 32wid..32wid+31
  int srl = lane >> 3;
  int clog = (lane & 7) ^ srl;
  int r_l = (srl << 1) | (clog >> 2);
  int q_l = clog & 3;
  const unsigned short* gA = A + (size_t)(slot0 + 32 * wid + r_l) * K + q_l * 8;
  const unsigned short* gB = Bp + (size_t)(n0 + 32 * wid + r_l) * K + q_l * 8;

#define STG(buf, kt) do {                                                \
    gld16(gA + (size_t)(kt) * 32, &lA[buf][(32 * wid) * 32]);            \
    gld16(gA + (size_t)16 * K + (size_t)(kt) * 32,                       \
          &lA[buf][(32 * wid + 16) * 32]);                               \
    gld16(gB + (size_t)(kt) * 32, &lB[buf][(32 * wid) * 32]);            \
    gld16(gB + (size_t)16 * K + (size_t)(kt) * 32,                       \
          &lB[buf][(32 * wid + 16) * 32]);                               \
  } while (0)
#define SYNC4 asm volatile("s_waitcnt vmcnt(4)\n\ts_barrier" ::: "memory")

  floatx4 acc[4][4];
#pragma unroll
  for (int mi = 0; mi < 4; mi++)
#pragma unroll
    for (int ni = 0; ni < 4; ni++) acc[mi][ni] = (floatx4){0.f, 0.f, 0.f, 0.f};

  constexpr int NK = K / 32;

  // prologue: stage K-steps 0,1; vmcnt(4) leaves step 1's group in flight
  STG(0, 0);
  STG(1, 1);
  SYNC4;

#define STEP(j, t) do {                                                  \
    int kt = ((t) + 2 < NK) ? (t) + 2 : 0;                               \
    STG(((j) + 2) % 3, kt);                                              \
    short8 af[4], bfr[4];                                                \
    _Pragma("unroll")                                                    \
    for (int m = 0; m < 4; m++) af[m] = *(const short8*)&lA[j][ra + m * 512]; \
    _Pragma("unroll")                                                    \
    for (int n = 0; n < 4; n++) bfr[n] = *(const short8*)&lB[j][rb + n * 512]; \
    _Pragma("unroll")                                                    \
    for (int m = 0; m < 4; m++)                                          \
      _Pragma("unroll")                                                  \
      for (int n = 0; n < 4; n++)                                        \
        acc[m][n] = __builtin_amdgcn_mfma_f32_16x16x32_bf16(af[m], bfr[n], acc[m][n], 0, 0, 0); \
    SYNC4;                                                               \
  } while (0)

  for (int t3 = 0; t3 < NK; t3 += 3) {
    STEP(0, t3);
    if (t3 + 1 < NK) STEP(1, t3 + 1);
    if (t3 + 2 < NK) STEP(2, t3 + 2);
  }
#undef STEP
#undef STG
#undef SYNC4

  const float* bias = bias_all + (size_t)e * N;
  if constexpr (ATOMIC) {
#pragma unroll
    for (int mi = 0; mi < 4; mi++) {
      int srow = slot0 + 64 * wr + 16 * mi + quad * 4;
#pragma unroll
      for (int r = 0; r < 4; r++) {
        int slot = srow + r;
        int tok = idxp[slot];
        tok = ((unsigned)tok < (unsigned)NT) ? tok : 0;
        float w = wtp[slot];
        float* orow = outp + (size_t)tok * D_;
#pragma unroll
        for (int ni = 0; ni < 4; ni++) {
          int col = n0 + 64 * wc + 16 * ni + l15;
          atomicAdd(&orow[col], w * (acc[mi][ni][r] + bias[col]));
        }
      }
    }
  } else {
#pragma unroll
    for (int mi = 0; mi < 4; mi++) {
      int row = slot0 + 64 * wr + 16 * mi + quad * 4;
#pragma unroll
      for (int ni = 0; ni < 4; ni++) {
        int col = n0 + 64 * wc + 16 * ni + l15;
        float bv = bias[col];
#pragma unroll
        for (int r = 0; r < 4; r++) {
          float v = acc[mi][ni][r] + bv;
          if (GELU) v = gelu_f(v);
          O[(size_t)(row + r) * N + col] = f2bf(v);
        }
      }
    }
  }
}

extern "C" void kernel_launch(void* const* d_in, const int* in_sizes, int n_in,
                              void* d_out, int out_size, void* d_ws, size_t ws_size,
                              hipStream_t stream) {
  const float* x  = (const float*)d_in[0];
  const float* gw = (const float*)d_in[1];
  const float* gb = (const float*)d_in[2];
  const float* w1 = (const float*)d_in[3];
  const float* b1 = (const float*)d_in[4];
  const float* w2 = (const float*)d_in[5];
  const float* b2 = (const float*)d_in[6];
  float* out = (float*)d_out;

  char* p = (char*)d_ws;
  unsigned short* w1t = (unsigned short*)p; p += (size_t)E_ * D_ * F_ * 2;
  unsigned short* w2t = (unsigned short*)p; p += (size_t)E_ * D_ * F_ * 2;
  unsigned short* Xg  = (unsigned short*)p; p += (size_t)CAP * D_ * 2;
  unsigned short* H   = (unsigned short*)p; p += (size_t)CAP * F_ * 2;
  int*   idx    = (int*)p; p += (size_t)CAP * 4;
  float* wt_of  = (float*)p; p += (size_t)CAP * 4;
  int*   ti     = (int*)p; p += (size_t)NS * 4;
  float* tw     = (float*)p; p += (size_t)NS * 4;
  int* cursors = (int*)p; p += 64;
  int* offs    = (int*)p; p += 64;

  transpose_cvt<<<dim3(1024, E_), 256, 0, stream>>>(w1, w2, w1t, w2t);
  router_k<<<NT / 4, 256, 0, stream>>>(x, gw, gb, ti, tw, out, wt_of);
  count_prefix_k<<<1, 256, 0, stream>>>(ti, offs, cursors);
  scatter_k<<<NS / 256, 256, 0, stream>>>(ti, tw, cursors, idx, wt_of);
  gather_k<<<CAP, 256, 0, stream>>>(x, idx, Xg);
  gemm_k<D_, F_, true, false><<<dim3((CAP / 128) * (F_ / 128)), 256, 0, stream>>>(
      Xg, w1t, b1, H, offs, nullptr, nullptr, nullptr);
  gemm_k<F_, D_, false, true><<<dim3((CAP / 128) * (D_ / 128)), 256, 0, stream>>>(
      H, w2t, b2, nullptr, offs, idx, wt_of, out);
}

// Round 9
// 458.551 us; speedup vs baseline: 2.1721x; 1.1707x over previous
//
#include <hip/hip_runtime.h>
#include <hip/hip_bf16.h>
#include <math.h>

#define B_ 4
#define T_ 2048
#define D_ 1024
#define F_ 2048
#define E_ 8
#define NT (B_ * T_)          // 8192 tokens
#define NS (NT * 2)           // 16384 routed assignments (K=2)
#define CAP (NS + E_ * 128)   // 17408 slots: 128-aligned per-expert segments always fit

typedef __attribute__((ext_vector_type(8))) short short8;
typedef __attribute__((ext_vector_type(4))) float floatx4;

static __device__ __forceinline__ unsigned short f2bf(float f) {
  union { float f; unsigned u; } a; a.f = f;
  unsigned r = a.u + 0x7fffu + ((a.u >> 16) & 1u);  // RNE
  return (unsigned short)(r >> 16);
}

static __device__ __forceinline__ float bf2f(unsigned u) {
  union { unsigned u; float f; } a; a.u = u << 16; return a.f;
}

static __device__ __forceinline__ void gld16(const unsigned short* g, unsigned short* l) {
  __builtin_amdgcn_global_load_lds(
      (const __attribute__((address_space(1))) void*)g,
      (__attribute__((address_space(3))) void*)l, 16, 0, 0);
}

// Branchless GELU: Abramowitz-Stegun 7.1.26 erf (|err| < 1.5e-7), hw exp2/rcp.
static __device__ __forceinline__ float gelu_f(float v) {
  float ax = fabsf(v) * 0.70710678118654752f;
  float t = __builtin_amdgcn_rcpf(1.f + 0.3275911f * ax);
  float e = __builtin_amdgcn_exp2f(-ax * ax * 1.44269504088896f);  // exp(-ax^2)
  float p = t * (0.254829592f +
            t * (-0.284496736f +
            t * (1.421413741f +
            t * (-1.453152027f +
            t * 1.061405429f))));
  float er = 1.f - p * e;
  er = copysignf(er, v);
  return 0.5f * v * (1.f + er);
}

// ---- weight transpose+convert into MFMA-fragment-packed layout, both weights
// in ONE launch (id<512 -> w1, else w2).
// Wp[e][n>>4][k>>5][lane][8] shorts, lane = 16*((k>>3)&3) + (n&15), inner = k&7.
// This is exactly the 16x16x32 bf16 B-fragment (lane 16*quad+l15 holds
// B[k0+8q..+8][ncol l15]) — so the GEMM loads each fragment as ONE coalesced
// 1KB global_load_dwordx4 (lane*16B), no LDS staging for B at all.
// Reads float4 coalesced; writes uint4 (16B) per thread, bijective per tile.
__global__ void transpose_cvt(const float* __restrict__ w1, const float* __restrict__ w2,
                              unsigned short* __restrict__ w1t, unsigned short* __restrict__ w2t) {
  __shared__ float tile[64][65];
  int id = blockIdx.x;              // 0..1023
  bool second = id >= 512;
  int lid = second ? id - 512 : id;
  int R = second ? F_ : D_, C = second ? D_ : F_;   // R = K-dim, C = N-dim
  int nx = C / 64;
  int ty = lid / nx, tx = lid - ty * nx;
  const float* inp = (second ? w2 : w1) + (size_t)blockIdx.y * R * C;
  unsigned short* outp = (second ? w2t : w1t) + (size_t)blockIdx.y * R * C;
  int c0 = tx * 64, r0 = ty * 64;
  int tid = threadIdx.x;            // 256
  int rl = tid >> 4;                // 0..15
  int cl = (tid & 15) * 4;          // 0,4,..,60
#pragma unroll
  for (int jr = 0; jr < 4; jr++) {
    int row = rl + 16 * jr;
    float4 v = *(const float4*)&inp[(size_t)(r0 + row) * C + c0 + cl];
    tile[row][cl + 0] = v.x; tile[row][cl + 1] = v.y;
    tile[row][cl + 2] = v.z; tile[row][cl + 3] = v.w;
  }
  __syncthreads();
  int cc0 = tid >> 3;               // 0..31
  int rq = (tid & 7) * 8;           // 0,8,..,56 (k base, 8 consecutive k)
#pragma unroll
  for (int jc = 0; jc < 2; jc++) {
    int cc = cc0 + 32 * jc;
    unsigned w[4];
#pragma unroll
    for (int i = 0; i < 4; i++) {
      unsigned lo = f2bf(tile[rq + 2 * i][cc]);       // k = kb+2i
      unsigned hi = f2bf(tile[rq + 2 * i + 1][cc]);   // k = kb+2i+1
      w[i] = lo | (hi << 16);
    }
    int n = c0 + cc, kb = r0 + rq;
    size_t soff = (size_t)(n >> 4) * ((size_t)R << 4)       // (n/16)*(K*16)
                + (size_t)(kb >> 5) * 512
                + (size_t)(((kb >> 3) & 3) * 16 + (n & 15)) * 8;
    *(uint4*)&outp[soff] = make_uint4(w[0], w[1], w[2], w[3]);
  }
}

// ---- router: fp32 logits, top-2, softmax over the pair. NO atomics. ----
__global__ void router_k(const float* __restrict__ x, const float* __restrict__ gw,
                         const float* __restrict__ gb, int* __restrict__ ti,
                         float* __restrict__ tw) {
  int wid = threadIdx.x >> 6, lane = threadIdx.x & 63;
  int t = blockIdx.x * 4 + wid;
  const float* xr = x + (size_t)t * D_;
  float acc[E_];
#pragma unroll
  for (int e = 0; e < E_; e++) acc[e] = 0.f;
#pragma unroll
  for (int it = 0; it < D_ / 64; it++) {
    int d = it * 64 + lane;
    float xv = xr[d];
    const float* g = gw + d * E_;
#pragma unroll
    for (int e = 0; e < E_; e++) acc[e] += xv * g[e];
  }
#pragma unroll
  for (int off = 32; off > 0; off >>= 1)
#pragma unroll
    for (int e = 0; e < E_; e++) acc[e] += __shfl_xor(acc[e], off);
  if (lane == 0) {
    float v[E_];
#pragma unroll
    for (int e = 0; e < E_; e++) v[e] = acc[e] + gb[e];
    int i0 = 0; float v0 = v[0];
#pragma unroll
    for (int e = 1; e < E_; e++) if (v[e] > v0) { v0 = v[e]; i0 = e; }
    int i1 = -1; float v1 = -3.4e38f;
#pragma unroll
    for (int e = 0; e < E_; e++) if (e != i0 && v[e] > v1) { v1 = v[e]; i1 = e; }
    float ex = expf(v1 - v0);           // <= 1, no overflow
    float w0 = 1.f / (1.f + ex);
    float w1 = ex / (1.f + ex);
    ti[2 * t] = i0; tw[2 * t] = w0;
    ti[2 * t + 1] = i1; tw[2 * t + 1] = w1;
  }
}

// ---- single-block histogram + 128-aligned exclusive prefix ----
__global__ void count_prefix_k(const int* __restrict__ ti, int* __restrict__ offs,
                               int* __restrict__ cursors) {
  __shared__ int scnt[4][E_];
  int tid = threadIdx.x;  // 256 threads
  int cnt[E_];
#pragma unroll
  for (int k = 0; k < E_; k++) cnt[k] = 0;
  for (int i = tid; i < NS; i += 256) {
    int e = ti[i];
#pragma unroll
    for (int k = 0; k < E_; k++) cnt[k] += (e == k) ? 1 : 0;
  }
#pragma unroll
  for (int off = 32; off > 0; off >>= 1)
#pragma unroll
    for (int k = 0; k < E_; k++) cnt[k] += __shfl_xor(cnt[k], off);
  int wid = tid >> 6, lane = tid & 63;
  if (lane == 0)
#pragma unroll
    for (int k = 0; k < E_; k++) scnt[wid][k] = cnt[k];
  __syncthreads();
  if (tid == 0) {
    int o = 0;
    for (int k = 0; k < E_; k++) {
      int c = scnt[0][k] + scnt[1][k] + scnt[2][k] + scnt[3][k];
      offs[k] = o;
      cursors[k] = o;
      o += (c + 127) & ~127;
    }
    offs[E_] = o;
  }
}

// ---- wave-aggregated scatter: 8 atomics per wave; records slot of each assignment ----
__global__ void scatter_k(const int* __restrict__ ti, const float* __restrict__ tw,
                          int* __restrict__ cursors, int* __restrict__ idx,
                          int* __restrict__ pos_of) {
  int a = blockIdx.x * 256 + threadIdx.x;  // 0..NS-1
  int lane = threadIdx.x & 63;
  int e = ti[a];
  unsigned long long m[E_];
#pragma unroll
  for (int k = 0; k < E_; k++) m[k] = __ballot(e == k);
  int base = 0;
  if (lane < E_) base = atomicAdd(&cursors[lane], __popcll(m[lane]));
  int myBase = __shfl(base, e);
  unsigned long long m_mine = 0;
#pragma unroll
  for (int k = 0; k < E_; k++) if (e == k) m_mine = m[k];
  int rank = __popcll(m_mine & ((1ull << lane) - 1ull));
  int pos = myBase + rank;
  idx[pos] = a >> 1;
  pos_of[a] = pos;
}

// ---- gather routed token rows into bf16, slot-major. Pad slots hold stale
// garbage in idx (no fill pass): clamp into [0,NT) — pads are never combined. ----
__global__ void gather_k(const float* __restrict__ x, const int* __restrict__ idx,
                         unsigned short* __restrict__ Xg) {
  int s = blockIdx.x;
  int t = idx[s];
  t = ((unsigned)t < (unsigned)NT) ? t : 0;
  const float4* xr = (const float4*)(x + (size_t)t * D_);
  float4 v = xr[threadIdx.x];
  uint2 p;
  p.x = (unsigned)f2bf(v.x) | ((unsigned)f2bf(v.y) << 16);
  p.y = (unsigned)f2bf(v.z) | ((unsigned)f2bf(v.w) << 16);
  ((uint2*)(Xg + (size_t)s * D_))[threadIdx.x] = p;
}

// ---- grouped GEMM: 128x128 tile, BK=32, 4 waves (2Mx2N).
// R5/R8 PMC analysis: LDS pipe was the binder (48 KB/block-step -> 384cyc vs
// 77cyc MFMA/SIMD => 25% MfmaUtil). This version removes B from LDS entirely:
// B comes fragment-packed from global (Wp layout, see transpose_cvt) as one
// coalesced 1KB dwordx4 per fragment into REGISTERS (bq0/bq1 double-buffer,
// compile-time indexed). LDS holds A only: 4-buffer rotation, 32 KB total.
// LDS/block-step: 24 KB (8 write + 16 read) -> ~192cyc; predicted MfmaUtil ~40%.
//
// Ledger per wave (counted vmcnt, never 0): entering step t, outstanding =
// A(t+1):2. Step t issues B(t+1):4 then A(t+2):2 -> 8; vmcnt(2) retires exactly
// {A(t+1), B(t+1)}; barrier publishes A(t+1) LDS. B-reg reads additionally
// guarded by compiler-inserted waits (safe if issue order drifts). Loop
// unrolled x4 so all LDS/reg buffer indices are compile-time (rule #20).
//
// __launch_bounds__(256,3): regs = 64 acc(AGPR) + ~100 arch (af 16 + bq 32 +
// addr) = ~164 <= 170 budget. R7 lesson: 4+ waves/EU spills acc -> never.
//
// + XCD swizzle (T1, R5-verified FETCH 300->83 MB) + A-LDS XOR swizzle
// (PMC-verified 0 conflicts), both unchanged.
template <int K, int N, bool GELU>
__global__ __launch_bounds__(256, 3) void gemm_k(const unsigned short* __restrict__ A,
                                                 const unsigned short* __restrict__ W,
                                                 const float* __restrict__ bias_all,
                                                 unsigned short* __restrict__ O,
                                                 const int* __restrict__ offs) {
  constexpr int NC = N / 128;
  constexpr int NK = K / 32;
  int h = blockIdx.x;
  int logical = (h & 7) * ((int)gridDim.x >> 3) + (h >> 3);
  int rt = logical / NC, ct = logical - rt * NC;   // NC is a power of 2
  int slot0 = rt * 128;
  if (slot0 >= offs[E_]) return;
  int e = 0;
  while (slot0 >= offs[e + 1]) e++;
  const unsigned short* gWp = W + (size_t)e * N * K;  // fragment-packed
  int n0 = ct * 128;

  __shared__ unsigned short lA[4][128 * 32];

  int tid = threadIdx.x;
  int wid = tid >> 6, lane = tid & 63;
  int wr = wid >> 1, wc = wid & 1;          // 2M x 2N wave grid, per-wave out 64x64
  int quad = lane >> 4, l15 = lane & 15;

  // A LDS read base: row r = 16-aligned base + l15 -> (r>>1)&7 = (l15>>1)&7
  int cph = (((l15 & 1) << 2) | quad) ^ ((l15 >> 1) & 7);
  int ra = ((wr << 5) + (l15 >> 1)) * 64 + cph * 8;   // + m*512 per 16-row frag

  // A staging lane map: lane i covers logical (r_l,q_l), c=(i&7)^(i>>3),
  // r_l=(i>>3)*2+(c>>2), q_l=c&3 (inverse of the read-side XOR swizzle)
  int srl = lane >> 3;
  int clog = (lane & 7) ^ srl;
  int r_l = (srl << 1) | (clog >> 2);
  int q_l = clog & 3;
  const unsigned short* gA = A + (size_t)(slot0 + 32 * wid + r_l) * K + q_l * 8;

  // B fragment tile base: n16 tiles (n0+64*wc)/16 + ni
  int n16b = (n0 >> 4) + (wc << 2);

  short8 bq0[4], bq1[4];
  floatx4 acc[4][4];
#pragma unroll
  for (int mi = 0; mi < 4; mi++)
#pragma unroll
    for (int ni = 0; ni < 4; ni++) acc[mi][ni] = (floatx4){0.f, 0.f, 0.f, 0.f};

#define STGA(buf, kt) do {                                               \
    gld16(gA + (size_t)(kt) * 32, &lA[buf][(32 * wid) * 32]);            \
    gld16(gA + (size_t)16 * K + (size_t)(kt) * 32,                       \
          &lA[buf][(32 * wid + 16) * 32]);                               \
  } while (0)
#define LOADB(dst, tt)                                                    \
    _Pragma("unroll")                                                     \
    for (int n_ = 0; n_ < 4; n_++)                                        \
      dst[n_] = *(const short8*)&gWp[((size_t)(n16b + n_) * NK + (tt)) * 512 + lane * 8]

  // prologue: A0->buf0, B0->bq0, A1->buf1; vmcnt(2) retires {A0,B0}, leaves A1
  STGA(0, 0);
  LOADB(bq0, 0);
  STGA(1, 1);
  asm volatile("s_waitcnt vmcnt(2)\n\ts_barrier" ::: "memory");

#define STEP(j, t, BR, BW) do {                                          \
    int bt = ((t) + 1 < NK) ? (t) + 1 : 0;  /* dummies keep ledger uniform */ \
    int kt = ((t) + 2 < NK) ? (t) + 2 : 0;                               \
    LOADB(BW, bt);                                                       \
    STGA((j + 2) & 3, kt);                                               \
    short8 af[4];                                                        \
    _Pragma("unroll")                                                    \
    for (int m = 0; m < 4; m++) af[m] = *(const short8*)&lA[j][ra + m * 512]; \
    _Pragma("unroll")                                                    \
    for (int m = 0; m < 4; m++)                                          \
      _Pragma("unroll")                                                  \
      for (int n_ = 0; n_ < 4; n_++)                                     \
        acc[m][n_] = __builtin_amdgcn_mfma_f32_16x16x32_bf16(af[m], BR[n_], acc[m][n_], 0, 0, 0); \
    asm volatile("s_waitcnt vmcnt(2)\n\ts_barrier" ::: "memory");        \
  } while (0)

  for (int t4 = 0; t4 < NK; t4 += 4) {  // NK = 32 or 64: divisible by 4
    STEP(0, t4,     bq0, bq1);
    STEP(1, t4 + 1, bq1, bq0);
    STEP(2, t4 + 2, bq0, bq1);
    STEP(3, t4 + 3, bq1, bq0);
  }
#undef STEP
#undef STGA
#undef LOADB

  const float* bias = bias_all + (size_t)e * N;
#pragma unroll
  for (int mi = 0; mi < 4; mi++) {
    int row = slot0 + 64 * wr + 16 * mi + quad * 4;
#pragma unroll
    for (int ni = 0; ni < 4; ni++) {
      int col = n0 + 64 * wc + 16 * ni + l15;
      float bv = bias[col];
#pragma unroll
      for (int r = 0; r < 4; r++) {
        float v = acc[mi][ni][r] + bv;
        if (GELU) v = gelu_f(v);
        O[(size_t)(row + r) * N + col] = f2bf(v);
      }
    }
  }
}

// ---- combine: out[t] = w0*Yg[pos(2t)] + w1*Yg[pos(2t+1)] ----
__global__ void combine_k(const unsigned short* __restrict__ Yg,
                          const int* __restrict__ pos_of,
                          const float* __restrict__ tw, float* __restrict__ out) {
  int t = blockIdx.x;
  int p0 = pos_of[2 * t], p1 = pos_of[2 * t + 1];
  float w0 = tw[2 * t], w1 = tw[2 * t + 1];
  uint2 a = ((const uint2*)(Yg + (size_t)p0 * D_))[threadIdx.x];
  uint2 b = ((const uint2*)(Yg + (size_t)p1 * D_))[threadIdx.x];
  float4 r;
  r.x = w0 * bf2f(a.x & 0xffffu) + w1 * bf2f(b.x & 0xffffu);
  r.y = w0 * bf2f(a.x >> 16)     + w1 * bf2f(b.x >> 16);
  r.z = w0 * bf2f(a.y & 0xffffu) + w1 * bf2f(b.y & 0xffffu);
  r.w = w0 * bf2f(a.y >> 16)     + w1 * bf2f(b.y >> 16);
  ((float4*)(out + (size_t)t * D_))[threadIdx.x] = r;
}

extern "C" void kernel_launch(void* const* d_in, const int* in_sizes, int n_in,
                              void* d_out, int out_size, void* d_ws, size_t ws_size,
                              hipStream_t stream) {
  const float* x  = (const float*)d_in[0];
  const float* gw = (const float*)d_in[1];
  const float* gb = (const float*)d_in[2];
  const float* w1 = (const float*)d_in[3];
  const float* b1 = (const float*)d_in[4];
  const float* w2 = (const float*)d_in[5];
  const float* b2 = (const float*)d_in[6];
  float* out = (float*)d_out;

  char* p = (char*)d_ws;
  unsigned short* w1t = (unsigned short*)p; p += (size_t)E_ * D_ * F_ * 2;
  unsigned short* w2t = (unsigned short*)p; p += (size_t)E_ * D_ * F_ * 2;
  unsigned short* Xg  = (unsigned short*)p; p += (size_t)CAP * D_ * 2;
  unsigned short* H   = (unsigned short*)p; p += (size_t)CAP * F_ * 2;
  int*   idx    = (int*)p; p += (size_t)CAP * 4;
  int*   pos_of = (int*)p; p += (size_t)NS * 4;
  int*   ti     = (int*)p; p += (size_t)NS * 4;
  float* tw     = (float*)p; p += (size_t)NS * 4;
  int* cursors = (int*)p; p += 64;
  int* offs    = (int*)p; p += 64;
  unsigned short* Yg = Xg;  // alias: Xg dead after gemm1, Yg born in gemm2

  transpose_cvt<<<dim3(1024, E_), 256, 0, stream>>>(w1, w2, w1t, w2t);
  router_k<<<NT / 4, 256, 0, stream>>>(x, gw, gb, ti, tw);
  count_prefix_k<<<1, 256, 0, stream>>>(ti, offs, cursors);
  scatter_k<<<NS / 256, 256, 0, stream>>>(ti, tw, cursors, idx, pos_of);
  gather_k<<<CAP, 256, 0, stream>>>(x, idx, Xg);
  gemm_k<D_, F_, true><<<dim3((CAP / 128) * (F_ / 128)), 256, 0, stream>>>(Xg, w1t, b1, H, offs);
  gemm_k<F_, D_, false><<<dim3((CAP / 128) * (D_ / 128)), 256, 0, stream>>>(H, w2t, b2, Yg, offs);
  combine_k<<<NT, 256, 0, stream>>>(Yg, pos_of, tw, out);
}